// Round 1
// baseline (1176.006 us; speedup 1.0000x reference)
//
#include <hip/hip_runtime.h>
#include <hip/hip_bf16.h>
#include <math.h>

#define DF 128          // feature dim
#define NLAYERS 5

// ---------------- CSR build ----------------

__global__ void hist_kernel(const int* __restrict__ dst, int* __restrict__ cnt, int E) {
    int i = blockIdx.x * blockDim.x + threadIdx.x;
    if (i < E) atomicAdd(&cnt[dst[i]], 1);
}

__global__ __launch_bounds__(1024) void scan_kernel(const int* __restrict__ cnt,
        int* __restrict__ off, int* __restrict__ cur, int n, int nedges) {
    __shared__ int sums[1024];
    int t = threadIdx.x;
    int chunk = (n + 1023) >> 10;
    int b = t * chunk;
    int e = min(b + chunk, n);
    int s = 0;
    for (int i = b; i < e; ++i) s += cnt[i];
    sums[t] = s;
    __syncthreads();
    // Hillis-Steele inclusive scan over 1024 partials
    for (int d = 1; d < 1024; d <<= 1) {
        int v = (t >= d) ? sums[t - d] : 0;
        __syncthreads();
        sums[t] += v;
        __syncthreads();
    }
    int run = (t > 0) ? sums[t - 1] : 0;   // exclusive prefix for this chunk
    for (int i = b; i < e; ++i) {
        off[i] = run;
        cur[i] = run;
        run += cnt[i];
    }
    if (t == 1023) off[n] = nedges;
}

__global__ void fill_kernel(const int* __restrict__ src, const int* __restrict__ dst,
        int* __restrict__ cur, int* __restrict__ csr, int E) {
    int i = blockIdx.x * blockDim.x + threadIdx.x;
    if (i < E) {
        int p = atomicAdd(&cur[dst[i]], 1);
        csr[p] = src[i];
    }
}

// ---------------- GEMM: h = x @ W^T + b ----------------
// Each lane owns one node; each block owns a 32-wide output chunk.
// W/bias addresses are block-uniform -> s_load; inner loop is v_fma with SGPR src.

__global__ __launch_bounds__(256) void gemm_kernel(const float* __restrict__ x,
        const float* __restrict__ W, const float* __restrict__ bias,
        float* __restrict__ h, int n) {
    int node = blockIdx.x * 256 + threadIdx.x;
    int oc = blockIdx.y * 32;
    bool valid = (node < n);
    const float* xrow = x + (size_t)(valid ? node : 0) * DF;

    float acc[32];
#pragma unroll
    for (int j = 0; j < 32; ++j) acc[j] = bias[oc + j];

#pragma unroll 1
    for (int kc = 0; kc < 4; ++kc) {
        float xr[32];
#pragma unroll
        for (int q = 0; q < 8; ++q) {
            float4 v = *reinterpret_cast<const float4*>(xrow + kc * 32 + q * 4);
            xr[q * 4 + 0] = v.x; xr[q * 4 + 1] = v.y;
            xr[q * 4 + 2] = v.z; xr[q * 4 + 3] = v.w;
        }
#pragma unroll
        for (int j = 0; j < 32; ++j) {
            const float* wrow = W + (size_t)(oc + j) * DF + kc * 32;
#pragma unroll
            for (int k = 0; k < 32; ++k) {
                acc[j] = fmaf(xr[k], wrow[k], acc[j]);
            }
        }
    }

    if (valid) {
        float* hrow = h + (size_t)node * DF + oc;
#pragma unroll
        for (int q = 0; q < 8; ++q) {
            float4 v = make_float4(acc[q * 4 + 0], acc[q * 4 + 1],
                                   acc[q * 4 + 2], acc[q * 4 + 3]);
            *reinterpret_cast<float4*>(hrow + q * 4) = v;
        }
    }
}

// ---------------- Aggregation: out[n][d] = max over in-edges of h[src][d] ----------------
// 256 threads = 2 nodes/block, 128 lanes per node (one lane per feature dim).

__global__ __launch_bounds__(256) void agg_kernel(const float* __restrict__ h,
        const int* __restrict__ off, const int* __restrict__ csr,
        float* __restrict__ out, int n, int do_silu) {
    int local = threadIdx.x >> 7;                 // 0 or 1
    int d = threadIdx.x & (DF - 1);
    int node = blockIdx.x * 2 + local;
    if (node >= n) return;

    int beg = off[node];
    int end = off[node + 1];
    float m = -INFINITY;
    int k = beg;
    for (; k + 1 < end; k += 2) {
        int s0 = csr[k];
        int s1 = csr[k + 1];
        float a = h[(size_t)s0 * DF + d];
        float b = h[(size_t)s1 * DF + d];
        m = fmaxf(m, fmaxf(a, b));
    }
    if (k < end) {
        int s0 = csr[k];
        m = fmaxf(m, h[(size_t)s0 * DF + d]);
    }
    float v = (beg == end) ? 0.0f : m;
    if (do_silu) v = v * (1.0f / (1.0f + __expf(-v)));
    out[(size_t)node * DF + d] = v;
}

// ---------------- Launch ----------------

extern "C" void kernel_launch(void* const* d_in, const int* in_sizes, int n_in,
                              void* d_out, int out_size, void* d_ws, size_t ws_size,
                              hipStream_t stream) {
    const float* x  = (const float*)d_in[0];
    const int*   ei = (const int*)d_in[1];
    const float* Ws = (const float*)d_in[2];
    const float* bs = (const float*)d_in[3];
    float* out = (float*)d_out;

    int N = in_sizes[0] / DF;
    int E = in_sizes[1] / 2;
    const int* src = ei;
    const int* dst = ei + E;

    // workspace carve (all 256B-aligned)
    char* w = (char*)d_ws;
    auto carve = [&](size_t bytes) {
        char* p = w;
        w += (bytes + 255) & ~(size_t)255;
        return p;
    };
    int*   cnt = (int*)carve((size_t)(N + 1) * sizeof(int));
    int*   off = (int*)carve((size_t)(N + 1) * sizeof(int));
    int*   cur = (int*)carve((size_t)(N + 1) * sizeof(int));
    int*   csr = (int*)carve((size_t)E * sizeof(int));
    float* h   = (float*)carve((size_t)N * DF * sizeof(float));
    float* xb  = (float*)carve((size_t)N * DF * sizeof(float));

    // ---- CSR build (once; reused by all 5 layers) ----
    hipMemsetAsync(cnt, 0, (size_t)N * sizeof(int), stream);
    hist_kernel<<<(E + 255) / 256, 256, 0, stream>>>(dst, cnt, E);
    scan_kernel<<<1, 1024, 0, stream>>>(cnt, off, cur, N, E);
    fill_kernel<<<(E + 255) / 256, 256, 0, stream>>>(src, dst, cur, csr, E);

    // ---- 5 layers ----
    dim3 ggrid((N + 255) / 256, 4);
    int agrid = (N + 1) / 2;
    for (int layer = 0; layer < NLAYERS; ++layer) {
        const float* xin = (layer == 0) ? x : xb;
        const float* Wl = Ws + (size_t)layer * DF * DF;
        const float* bl = bs + (size_t)layer * DF;
        gemm_kernel<<<ggrid, 256, 0, stream>>>(xin, Wl, bl, h, N);
        float* o = (layer == NLAYERS - 1) ? out : xb;
        int silu = (layer < NLAYERS - 1) ? 1 : 0;
        agg_kernel<<<agrid, 256, 0, stream>>>(h, off, csr, o, N, silu);
    }
}

// Round 2
// 902.022 us; speedup vs baseline: 1.3037x; 1.3037x over previous
//
#include <hip/hip_runtime.h>
#include <hip/hip_bf16.h>
#include <math.h>

#define DF 128          // feature dim
#define NLAYERS 5

// ---------------- CSR build ----------------

__global__ void hist_kernel(const int* __restrict__ dst, int* __restrict__ cnt, int E) {
    int i = blockIdx.x * blockDim.x + threadIdx.x;
    if (i < E) atomicAdd(&cnt[dst[i]], 1);
}

__global__ __launch_bounds__(1024) void scan_kernel(const int* __restrict__ cnt,
        int* __restrict__ off, int* __restrict__ cur, int n, int nedges) {
    __shared__ int sums[1024];
    int t = threadIdx.x;
    int chunk = (n + 1023) >> 10;
    int b = t * chunk;
    int e = min(b + chunk, n);
    int s = 0;
    for (int i = b; i < e; ++i) s += cnt[i];
    sums[t] = s;
    __syncthreads();
    for (int d = 1; d < 1024; d <<= 1) {
        int v = (t >= d) ? sums[t - d] : 0;
        __syncthreads();
        sums[t] += v;
        __syncthreads();
    }
    int run = (t > 0) ? sums[t - 1] : 0;
    for (int i = b; i < e; ++i) {
        off[i] = run;
        cur[i] = run;
        run += cnt[i];
    }
    if (t == 1023) off[n] = nedges;
}

__global__ void fill_kernel(const int* __restrict__ src, const int* __restrict__ dst,
        int* __restrict__ cur, int* __restrict__ csr, int E) {
    int i = blockIdx.x * blockDim.x + threadIdx.x;
    if (i < E) {
        int p = atomicAdd(&cur[dst[i]], 1);
        csr[p] = src[i];
    }
}

// ---------------- GEMM: h = x @ W^T + b ----------------
// Lane = one node; block-y = 16-wide output chunk (8 chunks).
// acc[16] + xr[32] ~ 58 VGPRs, launch_bounds(256,4) gives 128 VGPR budget so
// everything stays register-resident. W/bias are block-uniform -> s_load;
// inner loop is v_fmac_f32 with one SGPR operand (scalar pipe || VALU).

__global__ __launch_bounds__(256, 4) void gemm_kernel(const float* __restrict__ x,
        const float* __restrict__ W, const float* __restrict__ bias,
        float* __restrict__ h, int n) {
    int node = blockIdx.x * 256 + threadIdx.x;
    int oc = blockIdx.y * 16;
    bool valid = (node < n);
    const float* xrow = x + (size_t)(valid ? node : 0) * DF;

    float acc[16];
#pragma unroll
    for (int j = 0; j < 16; ++j) acc[j] = bias[oc + j];

#pragma unroll
    for (int kc = 0; kc < 4; ++kc) {
        float xr[32];
#pragma unroll
        for (int q = 0; q < 8; ++q) {
            float4 v = *reinterpret_cast<const float4*>(xrow + kc * 32 + q * 4);
            xr[q * 4 + 0] = v.x; xr[q * 4 + 1] = v.y;
            xr[q * 4 + 2] = v.z; xr[q * 4 + 3] = v.w;
        }
#pragma unroll
        for (int j = 0; j < 16; ++j) {
            const float* wrow = W + (oc + j) * DF + kc * 32;
#pragma unroll
            for (int k = 0; k < 32; ++k) {
                acc[j] = fmaf(xr[k], wrow[k], acc[j]);
            }
        }
    }

    if (valid) {
        float* hrow = h + (size_t)node * DF + oc;
#pragma unroll
        for (int q = 0; q < 4; ++q) {
            float4 v = make_float4(acc[q * 4 + 0], acc[q * 4 + 1],
                                   acc[q * 4 + 2], acc[q * 4 + 3]);
            *reinterpret_cast<float4*>(hrow + q * 4) = v;
        }
    }
}

// ---------------- Aggregation: out[n][d] = max over in-edges of h[src][d] ----------------
// One wave (64 lanes) per node, float2 per lane (512B/row coalesced).
// 4-edge unroll for memory-level parallelism against L2/L3 latency.

__global__ __launch_bounds__(256) void agg_kernel(const float* __restrict__ h,
        const int* __restrict__ off, const int* __restrict__ csr,
        float* __restrict__ out, int n, int do_silu) {
    int wid = threadIdx.x >> 6;
    int lane = threadIdx.x & 63;
    int node = blockIdx.x * 4 + wid;
    if (node >= n) return;

    const float2* h2 = (const float2*)h;
    int beg = off[node];
    int end = off[node + 1];

    float2 m = make_float2(-INFINITY, -INFINITY);
    int k = beg;
    for (; k + 3 < end; k += 4) {
        int s0 = csr[k], s1 = csr[k + 1], s2 = csr[k + 2], s3 = csr[k + 3];
        float2 a = h2[s0 * 64 + lane];
        float2 b = h2[s1 * 64 + lane];
        float2 c = h2[s2 * 64 + lane];
        float2 d = h2[s3 * 64 + lane];
        m.x = fmaxf(m.x, fmaxf(fmaxf(a.x, b.x), fmaxf(c.x, d.x)));
        m.y = fmaxf(m.y, fmaxf(fmaxf(a.y, b.y), fmaxf(c.y, d.y)));
    }
    for (; k < end; ++k) {
        int s0 = csr[k];
        float2 a = h2[s0 * 64 + lane];
        m.x = fmaxf(m.x, a.x);
        m.y = fmaxf(m.y, a.y);
    }
    if (beg == end) { m.x = 0.0f; m.y = 0.0f; }
    if (do_silu) {
        m.x = m.x * (1.0f / (1.0f + __expf(-m.x)));
        m.y = m.y * (1.0f / (1.0f + __expf(-m.y)));
    }
    reinterpret_cast<float2*>(out)[node * 64 + lane] = m;
}

// ---------------- Launch ----------------

extern "C" void kernel_launch(void* const* d_in, const int* in_sizes, int n_in,
                              void* d_out, int out_size, void* d_ws, size_t ws_size,
                              hipStream_t stream) {
    const float* x  = (const float*)d_in[0];
    const int*   ei = (const int*)d_in[1];
    const float* Ws = (const float*)d_in[2];
    const float* bs = (const float*)d_in[3];
    float* out = (float*)d_out;

    int N = in_sizes[0] / DF;
    int E = in_sizes[1] / 2;
    const int* src = ei;
    const int* dst = ei + E;

    char* w = (char*)d_ws;
    auto carve = [&](size_t bytes) {
        char* p = w;
        w += (bytes + 255) & ~(size_t)255;
        return p;
    };
    int*   cnt = (int*)carve((size_t)(N + 1) * sizeof(int));
    int*   off = (int*)carve((size_t)(N + 1) * sizeof(int));
    int*   cur = (int*)carve((size_t)(N + 1) * sizeof(int));
    int*   csr = (int*)carve((size_t)E * sizeof(int));
    float* h   = (float*)carve((size_t)N * DF * sizeof(float));
    float* xb  = (float*)carve((size_t)N * DF * sizeof(float));

    // ---- CSR build (once; reused by all 5 layers) ----
    hipMemsetAsync(cnt, 0, (size_t)N * sizeof(int), stream);
    hist_kernel<<<(E + 255) / 256, 256, 0, stream>>>(dst, cnt, E);
    scan_kernel<<<1, 1024, 0, stream>>>(cnt, off, cur, N, E);
    fill_kernel<<<(E + 255) / 256, 256, 0, stream>>>(src, dst, cur, csr, E);

    // ---- 5 layers ----
    dim3 ggrid((N + 255) / 256, 8);
    int agrid = (N + 3) / 4;
    for (int layer = 0; layer < NLAYERS; ++layer) {
        const float* xin = (layer == 0) ? x : xb;
        const float* Wl = Ws + (size_t)layer * DF * DF;
        const float* bl = bs + (size_t)layer * DF;
        gemm_kernel<<<ggrid, 256, 0, stream>>>(xin, Wl, bl, h, N);
        float* o = (layer == NLAYERS - 1) ? out : xb;
        int silu = (layer < NLAYERS - 1) ? 1 : 0;
        agg_kernel<<<agrid, 256, 0, stream>>>(h, off, csr, o, N, silu);
    }
}